// Round 13
// baseline (5829.290 us; speedup 1.0000x reference)
//
#include <hip/hip_runtime.h>
#include <hip/hip_bf16.h>

// LSTM (B=64,T=512,I=512,H=1024,O=1), 2 layers + sigmoid head.
// R13 = R12 + K-FUSED input transform: gates = [W_in | W_hh] @ [in; h_prev]
//   in ONE GEMM per step (K=1536 layer0, K=2048 layer1). The separate
//   "shadow" input GEMM -- which gated every WG's poll start -- is gone.
//  - Layer-pipelined: WGs 0..127 layer0 (step p), 128..255 layer1 (step p-2),
//    514 phases, one shared barrier. All inputs of step t are sealed by
//    wait(p): x static; h1[t+1] sealed at phase t+1 <= p-1; own state at p-1.
//  - Operand swap + zero-shuffle ew (R10), fragment-order conflict-free LDS
//    (R12), leader/release barrier (R12), R8 coherence protocol (sc0sc1 u64
//    write-through h stores, plain cached reads of FRESH reverse-order slabs,
//    RELAXED arrive, workgroup-scope acquire only).

namespace {

constexpr int B_ = 64, T_ = 512, I_ = 512, H_ = 1024;
constexpr int NWG = 256, NTHR = 256;
constexpr int BH = B_ * H_;

typedef __attribute__((ext_vector_type(8))) short short8;
typedef __attribute__((ext_vector_type(4))) float f32x4;

#define MFMA16(a, b, c) __builtin_amdgcn_mfma_f32_16x16x32_bf16((a), (b), (c), 0, 0, 0)

__device__ __forceinline__ float sigm(float x)  { return 1.f / (1.f + __expf(-x)); }
__device__ __forceinline__ float tanhx(float x) { return 2.f / (1.f + __expf(-2.f * x)) - 1.f; }

__device__ __forceinline__ unsigned f2bf(float f) {
  unsigned u = __float_as_uint(f);
  unsigned rnd = 0x7FFFu + ((u >> 16) & 1u);
  return (u + rnd) >> 16;   // low 16 bits valid
}
__device__ __forceinline__ float bf2f(unsigned short s) {
  return __uint_as_float(((unsigned)s) << 16);
}

__global__ void cvt_bf16_k(const float* __restrict__ src, unsigned short* __restrict__ dst, int n4) {
  int i = blockIdx.x * 256 + threadIdx.x;
  if (i >= n4) return;
  float4 v = reinterpret_cast<const float4*>(src)[i];
  ushort4 o;
  o.x = (unsigned short)f2bf(v.x); o.y = (unsigned short)f2bf(v.y);
  o.z = (unsigned short)f2bf(v.z); o.w = (unsigned short)f2bf(v.w);
  reinterpret_cast<ushort4*>(dst)[i] = o;
}

// zero slab-0 of both records (at REVERSED position T_) and the barrier region
__global__ void zero_init_k(unsigned short* __restrict__ h1, unsigned short* __restrict__ h2,
                            unsigned* __restrict__ bar) {
  int i = blockIdx.x * 256 + threadIdx.x;
  if (i < BH) h1[(size_t)T_ * BH + i] = 0;
  if (i < BH) h2[(size_t)T_ * BH + i] = 0;
  if (i < 2048) bar[i] = 0;   // 32 arrive lines + 8 release lines (stride 32)
}

// bars: arrive line g at bars[g*32] (g<32; 8 WGs each; monotonic: after all
// arrivals of phase p each == 8*(p+1)). Release line r at bars[1024+r*32]
// (r<8): leader wg==r posts the latest released phase.
// Records: slab s at rec + (T_-s)*BH (reverse order). Step t: read slab t,
// write slab t+1. Layer1's input h1[t] = h1 slab t+1.
__global__ __launch_bounds__(NTHR, 1) void lstm_fused(
    const unsigned short* __restrict__ xb,
    const unsigned short* __restrict__ wih0, const unsigned short* __restrict__ whh0,
    const float* __restrict__ bih0, const float* __restrict__ bhh0,
    const unsigned short* __restrict__ wih1, const unsigned short* __restrict__ whh1,
    const float* __restrict__ bih1, const float* __restrict__ bhh1,
    unsigned short* __restrict__ h1rec, unsigned short* __restrict__ h2rec,
    unsigned* __restrict__ bars)
{
  // fragment-order concat-W storage: slot ((rt*NKT+kk)*64+lane) holds the
  // 8 shorts lane needs for (row-tile rt, k-tile kk): row rt*16+(lane&15),
  // k-slice (lane>>4)*8 within the tile. Conflict-free wave reads.
  __shared__ unsigned short s_w[65536];   // 128 KB (layer0 uses 96 KB)

  const int tid   = threadIdx.x;
  const int wg    = blockIdx.x;       // 0..255
  const int layer = wg >> 7;          // 0..1
  const int lwg   = wg & 127;
  const int wave  = tid >> 6;         // 0..3 -> batch tile
  const int lane  = tid & 63;
  const int j0    = lwg * 8;          // first of 8 hidden units owned
  const int u4    = lane >> 4;        // unit offset in ew / k-group
  const int k0    = u4 * 8;
  const int arow  = wave * 16 + (lane & 15);   // batch row for B fragments

  const float* b_i = layer ? bih1 : bih0;
  const float* b_h = layer ? bhh1 : bhh0;
  unsigned short* rec = layer ? h2rec : h1rec;
  const int NKT = layer ? 64 : 48;    // concat K tiles (1536 / 2048)

  unsigned* grp = bars + (wg >> 3) * 32;
  unsigned* rel = bars + 1024 + (wg & 7) * 32;

  // ---- stage concat [W_in | W_hh] into fragment-order LDS ----
  for (int c = tid; c < 2 * NKT * 64; c += NTHR) {
    int l   = c & 63;
    int kkt = (c >> 6) % NKT;
    int rt  = c / (NKT * 64);
    int rr  = l & 15, q = l >> 4;
    int grow = (rr & 3) * H_ + j0 + rt * 4 + (rr >> 2);
    const unsigned short* src;
    if (layer == 0)
      src = (kkt < 16) ? &wih0[(size_t)grow * 512 + kkt * 32 + q * 8]
                       : &whh0[(size_t)grow * 1024 + (kkt - 16) * 32 + q * 8];
    else
      src = (kkt < 32) ? &wih1[(size_t)grow * 1024 + kkt * 32 + q * 8]
                       : &whh1[(size_t)grow * 1024 + (kkt - 32) * 32 + q * 8];
    *reinterpret_cast<short8*>(&s_w[c * 8]) = *reinterpret_cast<const short8*>(src);
  }
  float bias0[4], bias1[4];
  #pragma unroll
  for (int g = 0; g < 4; ++g) {
    bias0[g] = b_i[g * H_ + j0 + u4]     + b_h[g * H_ + j0 + u4];
    bias1[g] = b_i[g * H_ + j0 + 4 + u4] + b_h[g * H_ + j0 + 4 + u4];
  }
  __syncthreads();

  float cst0 = 0.f, cst1 = 0.f;

  for (int p = 0; p <= T_ + 1; ++p) {
    // ---- wait for phase p (leaders poll arrive lines; followers poll rel) ----
    if (p > 0) {
      const unsigned tgt = (unsigned)p * 8u;
      if (wg < 8) {
        if (wave == 0) {
          for (;;) {
            unsigned v = 0xFFFFFFFFu;
            if (lane < 32)
              v = __hip_atomic_load(bars + lane * 32, __ATOMIC_RELAXED, __HIP_MEMORY_SCOPE_AGENT);
            if (__all((int)(lane >= 32 || v >= tgt))) break;
            __builtin_amdgcn_s_sleep(1);
          }
          if (lane == 0)
            __hip_atomic_store(rel, (unsigned)p, __ATOMIC_RELAXED, __HIP_MEMORY_SCOPE_AGENT);
        } else {
          while (__hip_atomic_load(rel, __ATOMIC_RELAXED, __HIP_MEMORY_SCOPE_AGENT) < (unsigned)p)
            __builtin_amdgcn_s_sleep(1);
        }
      } else {
        while (__hip_atomic_load(rel, __ATOMIC_RELAXED, __HIP_MEMORY_SCOPE_AGENT) < (unsigned)p)
          __builtin_amdgcn_s_sleep(1);
      }
      __builtin_amdgcn_fence(__ATOMIC_ACQUIRE, "workgroup");  // ordering only, no cache ops
    }

    const int t = layer ? p - 2 : p;

    if (t >= 0 && t < T_) {
      f32x4 acc0 = {0.f, 0.f, 0.f, 0.f}, acc1 = {0.f, 0.f, 0.f, 0.f};

      if (layer == 0) {
        // B = [x[t]; h1 slab t] : 16 + 32 k-tiles
        const unsigned short* xr = xb + (size_t)arow * (T_ * I_) + (size_t)t * I_ + k0;
        const unsigned short* hr = h1rec + (size_t)(T_ - t) * BH + (size_t)arow * H_ + k0;
        short8 bf[48];
        #pragma unroll
        for (int kk = 0; kk < 16; ++kk)
          bf[kk] = *reinterpret_cast<const short8*>(xr + kk * 32);
        #pragma unroll
        for (int kk = 0; kk < 32; ++kk)
          bf[16 + kk] = *reinterpret_cast<const short8*>(hr + kk * 32);
        #pragma unroll
        for (int kk = 0; kk < 48; ++kk) {
          acc0 = MFMA16(*reinterpret_cast<const short8*>(&s_w[(kk * 64 + lane) * 8]),        bf[kk], acc0);
          acc1 = MFMA16(*reinterpret_cast<const short8*>(&s_w[((48 + kk) * 64 + lane) * 8]), bf[kk], acc1);
        }
      } else {
        // B = [h1 slab t+1 ; h2 slab t] : 32 + 32 k-tiles
        const unsigned short* ar = h1rec + (size_t)(T_ - t - 1) * BH + (size_t)arow * H_ + k0;
        const unsigned short* hr = h2rec + (size_t)(T_ - t) * BH + (size_t)arow * H_ + k0;
        short8 bf[64];
        #pragma unroll
        for (int kk = 0; kk < 32; ++kk)
          bf[kk] = *reinterpret_cast<const short8*>(ar + kk * 32);
        #pragma unroll
        for (int kk = 0; kk < 32; ++kk)
          bf[32 + kk] = *reinterpret_cast<const short8*>(hr + kk * 32);
        #pragma unroll
        for (int kk = 0; kk < 64; ++kk) {
          acc0 = MFMA16(*reinterpret_cast<const short8*>(&s_w[(kk * 64 + lane) * 8]),        bf[kk], acc0);
          acc1 = MFMA16(*reinterpret_cast<const short8*>(&s_w[((64 + kk) * 64 + lane) * 8]), bf[kk], acc1);
        }
      }

      // ---- elementwise (zero-shuffle): regs = gates of (unit, batch arow) ----
      float gi0 = sigm(acc0[0] + bias0[0]);
      float gf0 = sigm(acc0[1] + bias0[1]);
      float gg0 = tanhx(acc0[2] + bias0[2]);
      float go0 = sigm(acc0[3] + bias0[3]);
      cst0 = gf0 * cst0 + gi0 * gg0;
      float hv0 = go0 * tanhx(cst0);

      float gi1 = sigm(acc1[0] + bias1[0]);
      float gf1 = sigm(acc1[1] + bias1[1]);
      float gg1 = tanhx(acc1[2] + bias1[2]);
      float go1 = sigm(acc1[3] + bias1[3]);
      cst1 = gf1 * cst1 + gi1 * gg1;
      float hv1 = go1 * tanhx(cst1);

      // pack 4 units per tile into u64s on lanes 0..15, bypass stores
      unsigned a16 = f2bf(hv0) & 0xFFFFu;
      unsigned b16 = f2bf(hv1) & 0xFFFFu;
      unsigned a1 = __shfl(a16, (lane & 15) | 16, 64);
      unsigned a2 = __shfl(a16, (lane & 15) | 32, 64);
      unsigned a3 = __shfl(a16, (lane & 15) | 48, 64);
      unsigned b1 = __shfl(b16, (lane & 15) | 16, 64);
      unsigned b2 = __shfl(b16, (lane & 15) | 32, 64);
      unsigned b3 = __shfl(b16, (lane & 15) | 48, 64);
      if (lane < 16) {
        unsigned long long qa = (unsigned long long)(a16 | (a1 << 16)) |
                                ((unsigned long long)(a2 | (a3 << 16)) << 32);
        unsigned long long qb = (unsigned long long)(b16 | (b1 << 16)) |
                                ((unsigned long long)(b2 | (b3 << 16)) << 32);
        unsigned long long* dst = (unsigned long long*)
            (rec + (size_t)(T_ - t - 1) * BH + (size_t)(wave * 16 + lane) * H_ + j0);
        __hip_atomic_store(dst,     qa, __ATOMIC_RELAXED, __HIP_MEMORY_SCOPE_AGENT);
        __hip_atomic_store(dst + 1, qb, __ATOMIC_RELAXED, __HIP_MEMORY_SCOPE_AGENT);
      }
    }

    // ---- arrive: __syncthreads drains vmcnt(0) => stores ack'd at MALL ----
    __syncthreads();
    if (tid == 0)
      __hip_atomic_fetch_add(grp, 1u, __ATOMIC_RELAXED, __HIP_MEMORY_SCOPE_AGENT);
  }
}

__global__ void out_head(const unsigned short* __restrict__ h2,
                         const float* __restrict__ W_out,
                         const float* __restrict__ b_out,
                         float* __restrict__ out) {
  int b = blockIdx.x;      // 64
  int lane = threadIdx.x;  // 64 (one wave)
  float s = 0.f;
  for (int k = lane; k < H_; k += 64)
    s += bf2f(h2[(size_t)b * H_ + k]) * W_out[k];
  #pragma unroll
  for (int off = 32; off; off >>= 1) s += __shfl_down(s, off, 64);
  if (lane == 0) out[b] = sigm(s + b_out[0]);
}

} // namespace

extern "C" void kernel_launch(void* const* d_in, const int* in_sizes, int n_in,
                              void* d_out, int out_size, void* d_ws, size_t ws_size,
                              hipStream_t stream) {
  const float* x    = (const float*)d_in[0];
  const float* Wih0 = (const float*)d_in[1];
  const float* Whh0 = (const float*)d_in[2];
  const float* bih0 = (const float*)d_in[3];
  const float* bhh0 = (const float*)d_in[4];
  const float* Wih1 = (const float*)d_in[5];
  const float* Whh1 = (const float*)d_in[6];
  const float* bih1 = (const float*)d_in[7];
  const float* bhh1 = (const float*)d_in[8];
  const float* Wout = (const float*)d_in[9];
  const float* bout = (const float*)d_in[10];
  float* out = (float*)d_out;

  char* ws = (char*)d_ws;
  size_t off = 0;
  auto alloc = [&](size_t bytes) -> char* {
    char* p = ws + off;
    off += (bytes + 4095) & ~(size_t)4095;   // 4KB-align every region
    return p;
  };
  const size_t REC = (size_t)(T_ + 1) * BH * 2;       // 67.2 MB (513 slabs)

  unsigned* bar        = (unsigned*)alloc(8192);      // 2048 u32: arrive+release
  unsigned short* xb   = (unsigned short*)alloc((size_t)B_ * T_ * I_ * 2);
  unsigned short* wih0 = (unsigned short*)alloc((size_t)4 * H_ * I_ * 2);
  unsigned short* whh0 = (unsigned short*)alloc((size_t)4 * H_ * H_ * 2);
  unsigned short* wih1 = (unsigned short*)alloc((size_t)4 * H_ * H_ * 2);
  unsigned short* whh1 = (unsigned short*)alloc((size_t)4 * H_ * H_ * 2);
  unsigned short* h1   = (unsigned short*)alloc(REC);
  unsigned short* h2   = (unsigned short*)alloc(REC);

  auto cvt = [&](const float* s, unsigned short* d, int nelem) {
    int n4 = nelem / 4;
    cvt_bf16_k<<<(n4 + 255) / 256, 256, 0, stream>>>(s, d, n4);
  };
  cvt(x,    xb,   B_ * T_ * I_);
  cvt(Wih0, wih0, 4 * H_ * I_);
  cvt(Whh0, whh0, 4 * H_ * H_);
  cvt(Wih1, wih1, 4 * H_ * H_);
  cvt(Whh1, whh1, 4 * H_ * H_);
  zero_init_k<<<(BH + 255) / 256, 256, 0, stream>>>(h1, h2, bar);

  lstm_fused<<<NWG, NTHR, 0, stream>>>(
      xb, wih0, whh0, bih0, bhh0, wih1, whh1, bih1, bhh1, h1, h2, bar);

  // final h2 = layer1 step 511 output = slab 512 -> reversed offset 0
  out_head<<<B_, 64, 0, stream>>>(h2, Wout, bout, out);
}

// Round 14
// 5585.891 us; speedup vs baseline: 1.0436x; 1.0436x over previous
//
#include <hip/hip_runtime.h>
#include <hip/hip_bf16.h>

// LSTM (B=64,T=512,I=512,H=1024,O=1), 2 layers + sigmoid head.
// R14 = R12 (shadow in-GEMM, fragment-order LDS, leader/release barrier,
//       R8 coherence protocol) + DECOUPLED PER-LAYER BARRIERS.
//  - Layer0 (WGs 0..127) syncs only its own 128 WGs (16 arrive lines) -- it
//    never reads layer1 data, and all slabs are write-once so it can run
//    ahead freely.
//  - Layer1 (WGs 128..255) syncs its own 128 WGs for h2[t]; layer0 progress
//    (for h1 input) is checked via a slack-absorbing poll of layer0's arrive
//    lines in the SHADOW section (layer0 runs ahead -> usually free).
//  - R13's K-fusion reverted: the input GEMM lives in the shadow again
//    (R13 proved it costs 2.9us/phase when placed on the critical path).
//  - h protocol (R8): sc0sc1 u64 write-through stores, plain cached reads of
//    per-step FRESH slabs in REVERSE address order, RELAXED arrive RMW after
//    vmcnt-draining __syncthreads, workgroup-scope acquire fences only.

namespace {

constexpr int B_ = 64, T_ = 512, I_ = 512, H_ = 1024;
constexpr int NWG = 256, NTHR = 256;
constexpr int BH = B_ * H_;

typedef __attribute__((ext_vector_type(8))) short short8;
typedef __attribute__((ext_vector_type(4))) float f32x4;

#define MFMA16(a, b, c) __builtin_amdgcn_mfma_f32_16x16x32_bf16((a), (b), (c), 0, 0, 0)

__device__ __forceinline__ float sigm(float x)  { return 1.f / (1.f + __expf(-x)); }
__device__ __forceinline__ float tanhx(float x) { return 2.f / (1.f + __expf(-2.f * x)) - 1.f; }

__device__ __forceinline__ unsigned f2bf(float f) {
  unsigned u = __float_as_uint(f);
  unsigned rnd = 0x7FFFu + ((u >> 16) & 1u);
  return (u + rnd) >> 16;   // low 16 bits valid
}
__device__ __forceinline__ float bf2f(unsigned short s) {
  return __uint_as_float(((unsigned)s) << 16);
}

__global__ void cvt_bf16_k(const float* __restrict__ src, unsigned short* __restrict__ dst, int n4) {
  int i = blockIdx.x * 256 + threadIdx.x;
  if (i >= n4) return;
  float4 v = reinterpret_cast<const float4*>(src)[i];
  ushort4 o;
  o.x = (unsigned short)f2bf(v.x); o.y = (unsigned short)f2bf(v.y);
  o.z = (unsigned short)f2bf(v.z); o.w = (unsigned short)f2bf(v.w);
  reinterpret_cast<ushort4*>(dst)[i] = o;
}

// zero slab-0 of both records (at REVERSED position T_) and the barrier region
__global__ void zero_init_k(unsigned short* __restrict__ h1, unsigned short* __restrict__ h2,
                            unsigned* __restrict__ bar) {
  int i = blockIdx.x * 256 + threadIdx.x;
  if (i < BH) h1[(size_t)T_ * BH + i] = 0;
  if (i < BH) h2[(size_t)T_ * BH + i] = 0;
  if (i < 2048) bar[i] = 0;   // 32 arrive lines + 16 release lines (stride 32)
}

// bars: arrive line for layer L group g (8 WGs) at bars[(L*16+g)*32].
//   Monotonic: after all of layer L's arrivals for step t, each of its 16
//   counters == 8*(t+1). "Layer L done step t" <=> all 16 lines >= 8*(t+1).
// Release line r (leader lwg==r of layer L) at bars[1024 + (L*8+r)*32]:
//   holds the latest step t whose own-layer wait has been satisfied.
// Records: slab s at rec + (T_-s)*BH (reverse order). Step t: read slab t,
// write slab t+1. Layer1's input h1[t] = h1 slab t+1 (layer0 step t output).
__global__ __launch_bounds__(NTHR, 1) void lstm_fused(
    const unsigned short* __restrict__ xb,
    const unsigned short* __restrict__ wih0, const unsigned short* __restrict__ whh0,
    const float* __restrict__ bih0, const float* __restrict__ bhh0,
    const unsigned short* __restrict__ wih1, const unsigned short* __restrict__ whh1,
    const float* __restrict__ bih1, const float* __restrict__ bhh1,
    unsigned short* __restrict__ h1rec, unsigned short* __restrict__ h2rec,
    unsigned* __restrict__ bars)
{
  // fragment-order W storage: slot ((rt*NK+kk)*64+lane) holds 8 shorts =
  // row (rt*16 + lane&15), k-slice (lane>>4)*8 within k-tile kk.
  __shared__ unsigned short s_win[32768];   // 64 KB (layer0 uses half)
  __shared__ unsigned short s_whh[32768];   // 64 KB

  const int tid   = threadIdx.x;
  const int wg    = blockIdx.x;       // 0..255
  const int layer = wg >> 7;          // 0..1
  const int lwg   = wg & 127;
  const int wave  = tid >> 6;         // 0..3 -> batch tile
  const int lane  = tid & 63;
  const int j0    = lwg * 8;          // first of 8 hidden units owned
  const int u4    = lane >> 4;        // unit offset in ew / k-group
  const int k0    = u4 * 8;
  const int arow  = wave * 16 + (lane & 15);   // batch row for B fragments
  const int lbase = layer * 16;       // this layer's arrive-line base

  const unsigned short* w_in = layer ? wih1 : wih0;
  const unsigned short* w_hh = layer ? whh1 : whh0;
  const float* b_i = layer ? bih1 : bih0;
  const float* b_h = layer ? bhh1 : bhh0;
  unsigned short* rec = layer ? h2rec : h1rec;
  const int K_IN = layer ? 1024 : 512;
  const int NKI  = K_IN / 32;         // in-GEMM k-tiles (16 or 32)

  unsigned* grp = bars + (lbase + (lwg >> 3)) * 32;
  unsigned* rel = bars + 1024 + (layer * 8 + (lwg & 7)) * 32;

  // ---- stage W into fragment-order LDS ----
  for (int c = tid; c < 2 * NKI * 64; c += NTHR) {
    int l  = c & 63;
    int kk = (c >> 6) % NKI;
    int rt = c / (NKI * 64);
    int rr = l & 15, q = l >> 4;
    int grow = (rr & 3) * H_ + j0 + rt * 4 + (rr >> 2);
    *reinterpret_cast<short8*>(&s_win[c * 8]) =
        *reinterpret_cast<const short8*>(&w_in[(size_t)grow * K_IN + kk * 32 + q * 8]);
  }
  for (int c = tid; c < 2 * 32 * 64; c += NTHR) {
    int l  = c & 63;
    int kk = (c >> 6) & 31;
    int rt = c >> 11;
    int rr = l & 15, q = l >> 4;
    int grow = (rr & 3) * H_ + j0 + rt * 4 + (rr >> 2);
    *reinterpret_cast<short8*>(&s_whh[c * 8]) =
        *reinterpret_cast<const short8*>(&w_hh[(size_t)grow * H_ + kk * 32 + q * 8]);
  }
  float bias0[4], bias1[4];
  #pragma unroll
  for (int g = 0; g < 4; ++g) {
    bias0[g] = b_i[g * H_ + j0 + u4]     + b_h[g * H_ + j0 + u4];
    bias1[g] = b_i[g * H_ + j0 + 4 + u4] + b_h[g * H_ + j0 + 4 + u4];
  }
  __syncthreads();

  float cst0 = 0.f, cst1 = 0.f;
  f32x4 na0 = {0.f, 0.f, 0.f, 0.f}, na1 = {0.f, 0.f, 0.f, 0.f};

  // ---- prologue: in-acc for step 0 ----
  if (layer == 0) {
    const unsigned short* a_in = xb + (size_t)arow * (T_ * I_) + k0;
    #pragma unroll
    for (int kk = 0; kk < 16; ++kk) {
      short8 bv = *reinterpret_cast<const short8*>(a_in + kk * 32);
      na0 = MFMA16(*reinterpret_cast<const short8*>(&s_win[(kk * 64 + lane) * 8]),        bv, na0);
      na1 = MFMA16(*reinterpret_cast<const short8*>(&s_win[((16 + kk) * 64 + lane) * 8]), bv, na1);
    }
  } else {
    // need h1 slab 1 (layer0 step 0): wait L0 arrive lines >= 8
    for (;;) {
      unsigned v = 0xFFFFFFFFu;
      if (lane < 16)
        v = __hip_atomic_load(bars + lane * 32, __ATOMIC_RELAXED, __HIP_MEMORY_SCOPE_AGENT);
      if (__all((int)(lane >= 16 || v >= 8u))) break;
      __builtin_amdgcn_s_sleep(1);
    }
    __builtin_amdgcn_fence(__ATOMIC_ACQUIRE, "workgroup");
    const unsigned short* a_in = h1rec + (size_t)(T_ - 1) * BH + (size_t)arow * H_ + k0;
    #pragma unroll
    for (int kk = 0; kk < 32; ++kk) {
      short8 bv = *reinterpret_cast<const short8*>(a_in + kk * 32);
      na0 = MFMA16(*reinterpret_cast<const short8*>(&s_win[(kk * 64 + lane) * 8]),        bv, na0);
      na1 = MFMA16(*reinterpret_cast<const short8*>(&s_win[((32 + kk) * 64 + lane) * 8]), bv, na1);
    }
  }

  for (int t = 0; t < T_; ++t) {
    // ---- main wait: OWN layer's step t-1 complete (h slab t sealed) ----
    if (t > 0) {
      if (lwg < 8) {
        if (wave == 0) {
          const unsigned tgt = (unsigned)t * 8u;
          for (;;) {
            unsigned v = 0xFFFFFFFFu;
            if (lane < 16)
              v = __hip_atomic_load(bars + (lbase + lane) * 32, __ATOMIC_RELAXED, __HIP_MEMORY_SCOPE_AGENT);
            if (__all((int)(lane >= 16 || v >= tgt))) break;
            __builtin_amdgcn_s_sleep(1);
          }
          if (lane == 0)
            __hip_atomic_store(rel, (unsigned)t, __ATOMIC_RELAXED, __HIP_MEMORY_SCOPE_AGENT);
        } else {
          while (__hip_atomic_load(rel, __ATOMIC_RELAXED, __HIP_MEMORY_SCOPE_AGENT) < (unsigned)t)
            __builtin_amdgcn_s_sleep(1);
        }
      } else {
        while (__hip_atomic_load(rel, __ATOMIC_RELAXED, __HIP_MEMORY_SCOPE_AGENT) < (unsigned)t)
          __builtin_amdgcn_s_sleep(1);
      }
      __builtin_amdgcn_fence(__ATOMIC_ACQUIRE, "workgroup");  // ordering only, no cache ops
    }

    // ---- hh GEMM: B = own rec slab t (cached), A = s_whh fragments ----
    f32x4 acc0 = na0, acc1 = na1;
    {
      const unsigned short* a_h = rec + (size_t)(T_ - t) * BH + (size_t)arow * H_ + k0;
      short8 hf[32];
      #pragma unroll
      for (int kk = 0; kk < 32; ++kk)
        hf[kk] = *reinterpret_cast<const short8*>(a_h + kk * 32);
      #pragma unroll
      for (int kk = 0; kk < 32; ++kk) {
        acc0 = MFMA16(*reinterpret_cast<const short8*>(&s_whh[(kk * 64 + lane) * 8]),        hf[kk], acc0);
        acc1 = MFMA16(*reinterpret_cast<const short8*>(&s_whh[((32 + kk) * 64 + lane) * 8]), hf[kk], acc1);
      }
    }

    // ---- elementwise (zero-shuffle) ----
    float gi0 = sigm(acc0[0] + bias0[0]);
    float gf0 = sigm(acc0[1] + bias0[1]);
    float gg0 = tanhx(acc0[2] + bias0[2]);
    float go0 = sigm(acc0[3] + bias0[3]);
    cst0 = gf0 * cst0 + gi0 * gg0;
    float hv0 = go0 * tanhx(cst0);

    float gi1 = sigm(acc1[0] + bias1[0]);
    float gf1 = sigm(acc1[1] + bias1[1]);
    float gg1 = tanhx(acc1[2] + bias1[2]);
    float go1 = sigm(acc1[3] + bias1[3]);
    cst1 = gf1 * cst1 + gi1 * gg1;
    float hv1 = go1 * tanhx(cst1);

    unsigned a16 = f2bf(hv0) & 0xFFFFu;
    unsigned b16 = f2bf(hv1) & 0xFFFFu;
    unsigned a1 = __shfl(a16, (lane & 15) | 16, 64);
    unsigned a2 = __shfl(a16, (lane & 15) | 32, 64);
    unsigned a3 = __shfl(a16, (lane & 15) | 48, 64);
    unsigned b1 = __shfl(b16, (lane & 15) | 16, 64);
    unsigned b2 = __shfl(b16, (lane & 15) | 32, 64);
    unsigned b3 = __shfl(b16, (lane & 15) | 48, 64);
    if (lane < 16) {
      unsigned long long qa = (unsigned long long)(a16 | (a1 << 16)) |
                              ((unsigned long long)(a2 | (a3 << 16)) << 32);
      unsigned long long qb = (unsigned long long)(b16 | (b1 << 16)) |
                              ((unsigned long long)(b2 | (b3 << 16)) << 32);
      unsigned long long* dst = (unsigned long long*)
          (rec + (size_t)(T_ - t - 1) * BH + (size_t)(wave * 16 + lane) * H_ + j0);
      __hip_atomic_store(dst,     qa, __ATOMIC_RELAXED, __HIP_MEMORY_SCOPE_AGENT);
      __hip_atomic_store(dst + 1, qb, __ATOMIC_RELAXED, __HIP_MEMORY_SCOPE_AGENT);
    }

    // ---- arrive: __syncthreads drains vmcnt(0) => stores ack'd at MALL ----
    __syncthreads();
    if (tid == 0)
      __hip_atomic_fetch_add(grp, 1u, __ATOMIC_RELAXED, __HIP_MEMORY_SCOPE_AGENT);

    // ---- shadow: in-GEMM for step t+1 (off the critical path) ----
    na0 = (f32x4){0.f, 0.f, 0.f, 0.f};
    na1 = (f32x4){0.f, 0.f, 0.f, 0.f};
    const int tn = t + 1;
    if (tn < T_) {
      if (layer == 0) {
        const unsigned short* a_in = xb + (size_t)arow * (T_ * I_) + (size_t)tn * I_ + k0;
        #pragma unroll
        for (int kk = 0; kk < 16; ++kk) {
          short8 bv = *reinterpret_cast<const short8*>(a_in + kk * 32);
          na0 = MFMA16(*reinterpret_cast<const short8*>(&s_win[(kk * 64 + lane) * 8]),        bv, na0);
          na1 = MFMA16(*reinterpret_cast<const short8*>(&s_win[((16 + kk) * 64 + lane) * 8]), bv, na1);
        }
      } else {
        // input = h1 slab tn+1: wait layer0 arrive lines >= 8*(tn+1).
        // Layer0 runs ahead, so this poll usually passes immediately.
        const unsigned tgt0 = (unsigned)(tn + 1) * 8u;
        for (;;) {
          unsigned v = 0xFFFFFFFFu;
          if (lane < 16)
            v = __hip_atomic_load(bars + lane * 32, __ATOMIC_RELAXED, __HIP_MEMORY_SCOPE_AGENT);
          if (__all((int)(lane >= 16 || v >= tgt0))) break;
          __builtin_amdgcn_s_sleep(1);
        }
        __builtin_amdgcn_fence(__ATOMIC_ACQUIRE, "workgroup");
        const unsigned short* a_in = h1rec + (size_t)(T_ - 1 - tn) * BH + (size_t)arow * H_ + k0;
        #pragma unroll
        for (int kk = 0; kk < 32; ++kk) {
          short8 bv = *reinterpret_cast<const short8*>(a_in + kk * 32);
          na0 = MFMA16(*reinterpret_cast<const short8*>(&s_win[(kk * 64 + lane) * 8]),        bv, na0);
          na1 = MFMA16(*reinterpret_cast<const short8*>(&s_win[((32 + kk) * 64 + lane) * 8]), bv, na1);
        }
      }
    }
  }
}

__global__ void out_head(const unsigned short* __restrict__ h2,
                         const float* __restrict__ W_out,
                         const float* __restrict__ b_out,
                         float* __restrict__ out) {
  int b = blockIdx.x;      // 64
  int lane = threadIdx.x;  // 64 (one wave)
  float s = 0.f;
  for (int k = lane; k < H_; k += 64)
    s += bf2f(h2[(size_t)b * H_ + k]) * W_out[k];
  #pragma unroll
  for (int off = 32; off; off >>= 1) s += __shfl_down(s, off, 64);
  if (lane == 0) out[b] = sigm(s + b_out[0]);
}

} // namespace

extern "C" void kernel_launch(void* const* d_in, const int* in_sizes, int n_in,
                              void* d_out, int out_size, void* d_ws, size_t ws_size,
                              hipStream_t stream) {
  const float* x    = (const float*)d_in[0];
  const float* Wih0 = (const float*)d_in[1];
  const float* Whh0 = (const float*)d_in[2];
  const float* bih0 = (const float*)d_in[3];
  const float* bhh0 = (const float*)d_in[4];
  const float* Wih1 = (const float*)d_in[5];
  const float* Whh1 = (const float*)d_in[6];
  const float* bih1 = (const float*)d_in[7];
  const float* bhh1 = (const float*)d_in[8];
  const float* Wout = (const float*)d_in[9];
  const float* bout = (const float*)d_in[10];
  float* out = (float*)d_out;

  char* ws = (char*)d_ws;
  size_t off = 0;
  auto alloc = [&](size_t bytes) -> char* {
    char* p = ws + off;
    off += (bytes + 4095) & ~(size_t)4095;   // 4KB-align every region
    return p;
  };
  const size_t REC = (size_t)(T_ + 1) * BH * 2;       // 67.2 MB (513 slabs)

  unsigned* bar        = (unsigned*)alloc(8192);      // 2048 u32: arrive+release
  unsigned short* xb   = (unsigned short*)alloc((size_t)B_ * T_ * I_ * 2);
  unsigned short* wih0 = (unsigned short*)alloc((size_t)4 * H_ * I_ * 2);
  unsigned short* whh0 = (unsigned short*)alloc((size_t)4 * H_ * H_ * 2);
  unsigned short* wih1 = (unsigned short*)alloc((size_t)4 * H_ * H_ * 2);
  unsigned short* whh1 = (unsigned short*)alloc((size_t)4 * H_ * H_ * 2);
  unsigned short* h1   = (unsigned short*)alloc(REC);
  unsigned short* h2   = (unsigned short*)alloc(REC);

  auto cvt = [&](const float* s, unsigned short* d, int nelem) {
    int n4 = nelem / 4;
    cvt_bf16_k<<<(n4 + 255) / 256, 256, 0, stream>>>(s, d, n4);
  };
  cvt(x,    xb,   B_ * T_ * I_);
  cvt(Wih0, wih0, 4 * H_ * I_);
  cvt(Whh0, whh0, 4 * H_ * H_);
  cvt(Wih1, wih1, 4 * H_ * H_);
  cvt(Whh1, whh1, 4 * H_ * H_);
  zero_init_k<<<(BH + 255) / 256, 256, 0, stream>>>(h1, h2, bar);

  lstm_fused<<<NWG, NTHR, 0, stream>>>(
      xb, wih0, whh0, bih0, bhh0, wih1, whh1, bih1, bhh1, h1, h2, bar);

  // final h2 = layer1 step 511 output = slab 512 -> reversed offset 0
  out_head<<<B_, 64, 0, stream>>>(h2, Wout, bout, out);
}

// Round 15
// 4837.331 us; speedup vs baseline: 1.2051x; 1.1547x over previous
//
#include <hip/hip_runtime.h>
#include <hip/hip_bf16.h>

// LSTM (B=64,T=512,I=512,H=1024,O=1), 2 layers + sigmoid head.
// R15 = R12 (best: 4.27ms) + shadow-GEMM LOAD PREFETCH:
//   the next-step input-GEMM's B-fragments are loaded BEFORE __syncthreads
//   (absorbed into the vmcnt(0) drain we already pay; data sealed by wait(p)),
//   so the post-arrive shadow is pure MFMAs and fits inside the barrier's
//   release-propagation latency. R14 proved the shadow window is what hides
//   the in-GEMM; this makes the hiding robust.
//  - Layer-pipelined: WGs 0..127 layer0 (step p), 128..255 layer1 (step p-2),
//    514 phases, ONE coupled 256-WG barrier (R14's decoupling regressed).
//  - Operand swap + zero-shuffle ew (R10), fragment-order conflict-free LDS
//    (R12), 8-leader release lines (R12), R8 coherence protocol (sc0sc1 u64
//    write-through h stores, cached reads of FRESH reverse-order slabs,
//    RELAXED arrive, workgroup-scope acquire fences only).

namespace {

constexpr int B_ = 64, T_ = 512, I_ = 512, H_ = 1024;
constexpr int NWG = 256, NTHR = 256;
constexpr int BH = B_ * H_;

typedef __attribute__((ext_vector_type(8))) short short8;
typedef __attribute__((ext_vector_type(4))) float f32x4;

#define MFMA16(a, b, c) __builtin_amdgcn_mfma_f32_16x16x32_bf16((a), (b), (c), 0, 0, 0)

__device__ __forceinline__ float sigm(float x)  { return 1.f / (1.f + __expf(-x)); }
__device__ __forceinline__ float tanhx(float x) { return 2.f / (1.f + __expf(-2.f * x)) - 1.f; }

__device__ __forceinline__ unsigned f2bf(float f) {
  unsigned u = __float_as_uint(f);
  unsigned rnd = 0x7FFFu + ((u >> 16) & 1u);
  return (u + rnd) >> 16;   // low 16 bits valid
}
__device__ __forceinline__ float bf2f(unsigned short s) {
  return __uint_as_float(((unsigned)s) << 16);
}

__global__ void cvt_bf16_k(const float* __restrict__ src, unsigned short* __restrict__ dst, int n4) {
  int i = blockIdx.x * 256 + threadIdx.x;
  if (i >= n4) return;
  float4 v = reinterpret_cast<const float4*>(src)[i];
  ushort4 o;
  o.x = (unsigned short)f2bf(v.x); o.y = (unsigned short)f2bf(v.y);
  o.z = (unsigned short)f2bf(v.z); o.w = (unsigned short)f2bf(v.w);
  reinterpret_cast<ushort4*>(dst)[i] = o;
}

// zero slab-0 of both records (at REVERSED position T_) and the barrier region
__global__ void zero_init_k(unsigned short* __restrict__ h1, unsigned short* __restrict__ h2,
                            unsigned* __restrict__ bar) {
  int i = blockIdx.x * 256 + threadIdx.x;
  if (i < BH) h1[(size_t)T_ * BH + i] = 0;
  if (i < BH) h2[(size_t)T_ * BH + i] = 0;
  if (i < 2048) bar[i] = 0;   // 32 arrive lines + 8 release lines (stride 32)
}

// bars: arrive line g at bars[g*32] (g<32; 8 WGs each; monotonic: after all
// arrivals of phase p each == 8*(p+1)). Release line r at bars[1024+r*32]
// (r<8): leader wg==r posts the latest released phase.
// Records: slab s at rec + (T_-s)*BH (reverse order). Step t: read slab t,
// write slab t+1. Layer1's step-t input = h1 slab t+1.
__global__ __launch_bounds__(NTHR, 1) void lstm_fused(
    const unsigned short* __restrict__ xb,
    const unsigned short* __restrict__ wih0, const unsigned short* __restrict__ whh0,
    const float* __restrict__ bih0, const float* __restrict__ bhh0,
    const unsigned short* __restrict__ wih1, const unsigned short* __restrict__ whh1,
    const float* __restrict__ bih1, const float* __restrict__ bhh1,
    unsigned short* __restrict__ h1rec, unsigned short* __restrict__ h2rec,
    unsigned* __restrict__ bars)
{
  // fragment-order W storage: slot ((rt*NK+kk)*64+lane) holds 8 shorts =
  // row (rt*16 + lane&15), k-slice (lane>>4)*8 within k-tile kk.
  __shared__ unsigned short s_win[32768];   // 64 KB (layer0 uses half)
  __shared__ unsigned short s_whh[32768];   // 64 KB

  const int tid   = threadIdx.x;
  const int wg    = blockIdx.x;       // 0..255
  const int layer = wg >> 7;          // 0..1
  const int lwg   = wg & 127;
  const int wave  = tid >> 6;         // 0..3 -> batch tile
  const int lane  = tid & 63;
  const int j0    = lwg * 8;          // first of 8 hidden units owned
  const int u4    = lane >> 4;        // k-group / unit offset in ew
  const int k0    = u4 * 8;
  const int arow  = wave * 16 + (lane & 15);   // batch row for B fragments

  const unsigned short* w_in = layer ? wih1 : wih0;
  const unsigned short* w_hh = layer ? whh1 : whh0;
  const float* b_i = layer ? bih1 : bih0;
  const float* b_h = layer ? bhh1 : bhh0;
  unsigned short* rec = layer ? h2rec : h1rec;
  const int K_IN = layer ? 1024 : 512;
  const int NKI  = K_IN / 32;         // in-GEMM k-tiles (16 or 32)

  unsigned* grp = bars + (wg >> 3) * 32;
  unsigned* rel = bars + 1024 + (wg & 7) * 32;

  // ---- stage W into fragment-order LDS ----
  for (int c = tid; c < 2 * NKI * 64; c += NTHR) {
    int l  = c & 63;
    int kk = (c >> 6) % NKI;
    int rt = c / (NKI * 64);
    int rr = l & 15, q = l >> 4;
    int grow = (rr & 3) * H_ + j0 + rt * 4 + (rr >> 2);
    *reinterpret_cast<short8*>(&s_win[c * 8]) =
        *reinterpret_cast<const short8*>(&w_in[(size_t)grow * K_IN + kk * 32 + q * 8]);
  }
  for (int c = tid; c < 2 * 32 * 64; c += NTHR) {
    int l  = c & 63;
    int kk = (c >> 6) & 31;
    int rt = c >> 11;
    int rr = l & 15, q = l >> 4;
    int grow = (rr & 3) * H_ + j0 + rt * 4 + (rr >> 2);
    *reinterpret_cast<short8*>(&s_whh[c * 8]) =
        *reinterpret_cast<const short8*>(&w_hh[(size_t)grow * H_ + kk * 32 + q * 8]);
  }
  float bias0[4], bias1[4];
  #pragma unroll
  for (int g = 0; g < 4; ++g) {
    bias0[g] = b_i[g * H_ + j0 + u4]     + b_h[g * H_ + j0 + u4];
    bias1[g] = b_i[g * H_ + j0 + 4 + u4] + b_h[g * H_ + j0 + 4 + u4];
  }
  __syncthreads();

  float cst0 = 0.f, cst1 = 0.f;
  f32x4 na0 = {0.f, 0.f, 0.f, 0.f}, na1 = {0.f, 0.f, 0.f, 0.f};

  // prologue: layer0's in-acc for step 0
  if (layer == 0) {
    const unsigned short* a_in = xb + (size_t)arow * (T_ * I_) + k0;
    #pragma unroll
    for (int kk = 0; kk < 16; ++kk) {
      short8 bv = *reinterpret_cast<const short8*>(a_in + kk * 32);
      na0 = MFMA16(*reinterpret_cast<const short8*>(&s_win[(kk * 64 + lane) * 8]),        bv, na0);
      na1 = MFMA16(*reinterpret_cast<const short8*>(&s_win[((16 + kk) * 64 + lane) * 8]), bv, na1);
    }
  }

  for (int p = 0; p <= T_ + 1; ++p) {
    // ---- wait for phase p (leaders poll arrive lines; followers poll rel) ----
    if (p > 0) {
      const unsigned tgt = (unsigned)p * 8u;
      if (wg < 8) {
        if (wave == 0) {
          for (;;) {
            unsigned v = 0xFFFFFFFFu;
            if (lane < 32)
              v = __hip_atomic_load(bars + lane * 32, __ATOMIC_RELAXED, __HIP_MEMORY_SCOPE_AGENT);
            if (__all((int)(lane >= 32 || v >= tgt))) break;
            __builtin_amdgcn_s_sleep(1);
          }
          if (lane == 0)
            __hip_atomic_store(rel, (unsigned)p, __ATOMIC_RELAXED, __HIP_MEMORY_SCOPE_AGENT);
        } else {
          while (__hip_atomic_load(rel, __ATOMIC_RELAXED, __HIP_MEMORY_SCOPE_AGENT) < (unsigned)p)
            __builtin_amdgcn_s_sleep(1);
        }
      } else {
        while (__hip_atomic_load(rel, __ATOMIC_RELAXED, __HIP_MEMORY_SCOPE_AGENT) < (unsigned)p)
          __builtin_amdgcn_s_sleep(1);
      }
      __builtin_amdgcn_fence(__ATOMIC_ACQUIRE, "workgroup");  // ordering only, no cache ops
    }

    f32x4 acc0 = na0, acc1 = na1;
    const int t = layer ? p - 2 : p;

    if (t >= 0 && t < T_) {
      // ---- hh GEMM: B = h[slab t] (cached), A = s_whh fragments ----
      const unsigned short* a_h = rec + (size_t)(T_ - t) * BH + (size_t)arow * H_ + k0;
      short8 hf[32];
      #pragma unroll
      for (int kk = 0; kk < 32; ++kk)
        hf[kk] = *reinterpret_cast<const short8*>(a_h + kk * 32);
      #pragma unroll
      for (int kk = 0; kk < 32; ++kk) {
        acc0 = MFMA16(*reinterpret_cast<const short8*>(&s_whh[(kk * 64 + lane) * 8]),        hf[kk], acc0);
        acc1 = MFMA16(*reinterpret_cast<const short8*>(&s_whh[((32 + kk) * 64 + lane) * 8]), hf[kk], acc1);
      }

      // ---- elementwise (zero-shuffle) ----
      float gi0 = sigm(acc0[0] + bias0[0]);
      float gf0 = sigm(acc0[1] + bias0[1]);
      float gg0 = tanhx(acc0[2] + bias0[2]);
      float go0 = sigm(acc0[3] + bias0[3]);
      cst0 = gf0 * cst0 + gi0 * gg0;
      float hv0 = go0 * tanhx(cst0);

      float gi1 = sigm(acc1[0] + bias1[0]);
      float gf1 = sigm(acc1[1] + bias1[1]);
      float gg1 = tanhx(acc1[2] + bias1[2]);
      float go1 = sigm(acc1[3] + bias1[3]);
      cst1 = gf1 * cst1 + gi1 * gg1;
      float hv1 = go1 * tanhx(cst1);

      unsigned a16 = f2bf(hv0) & 0xFFFFu;
      unsigned b16 = f2bf(hv1) & 0xFFFFu;
      unsigned a1 = __shfl(a16, (lane & 15) | 16, 64);
      unsigned a2 = __shfl(a16, (lane & 15) | 32, 64);
      unsigned a3 = __shfl(a16, (lane & 15) | 48, 64);
      unsigned b1 = __shfl(b16, (lane & 15) | 16, 64);
      unsigned b2 = __shfl(b16, (lane & 15) | 32, 64);
      unsigned b3 = __shfl(b16, (lane & 15) | 48, 64);
      if (lane < 16) {
        unsigned long long qa = (unsigned long long)(a16 | (a1 << 16)) |
                                ((unsigned long long)(a2 | (a3 << 16)) << 32);
        unsigned long long qb = (unsigned long long)(b16 | (b1 << 16)) |
                                ((unsigned long long)(b2 | (b3 << 16)) << 32);
        unsigned long long* dst = (unsigned long long*)
            (rec + (size_t)(T_ - t - 1) * BH + (size_t)(wave * 16 + lane) * H_ + j0);
        __hip_atomic_store(dst,     qa, __ATOMIC_RELAXED, __HIP_MEMORY_SCOPE_AGENT);
        __hip_atomic_store(dst + 1, qb, __ATOMIC_RELAXED, __HIP_MEMORY_SCOPE_AGENT);
      }
    }

    // ---- PREFETCH next in-GEMM B-fragments BEFORE the barrier: the loads
    //      complete during the vmcnt(0) drain + arrive + release window.
    //      Data is sealed by wait(p) (x static; h1 slab p written phase p-1).
    const int tn = layer ? p - 1 : p + 1;
    short8 nf[32];
    if (tn >= 0 && tn < T_) {
      if (layer == 0) {
        const unsigned short* a_in = xb + (size_t)arow * (T_ * I_) + (size_t)tn * I_ + k0;
        #pragma unroll
        for (int kk = 0; kk < 16; ++kk)
          nf[kk] = *reinterpret_cast<const short8*>(a_in + kk * 32);
      } else {
        const unsigned short* a_in = h1rec + (size_t)(T_ - 1 - tn) * BH + (size_t)arow * H_ + k0;
        #pragma unroll
        for (int kk = 0; kk < 32; ++kk)
          nf[kk] = *reinterpret_cast<const short8*>(a_in + kk * 32);
      }
    }

    // ---- arrive: __syncthreads drains vmcnt(0) => stores ack'd at MALL,
    //      prefetch loads complete. RELAXED RMW (no wbl2). ----
    __syncthreads();
    if (tid == 0)
      __hip_atomic_fetch_add(grp, 1u, __ATOMIC_RELAXED, __HIP_MEMORY_SCOPE_AGENT);

    // ---- shadow: in-GEMM MFMAs only (loads already in registers) ----
    na0 = (f32x4){0.f, 0.f, 0.f, 0.f};
    na1 = (f32x4){0.f, 0.f, 0.f, 0.f};
    if (tn >= 0 && tn < T_) {
      if (layer == 0) {
        #pragma unroll
        for (int kk = 0; kk < 16; ++kk) {
          na0 = MFMA16(*reinterpret_cast<const short8*>(&s_win[(kk * 64 + lane) * 8]),        nf[kk], na0);
          na1 = MFMA16(*reinterpret_cast<const short8*>(&s_win[((16 + kk) * 64 + lane) * 8]), nf[kk], na1);
        }
      } else {
        #pragma unroll
        for (int kk = 0; kk < 32; ++kk) {
          na0 = MFMA16(*reinterpret_cast<const short8*>(&s_win[(kk * 64 + lane) * 8]),        nf[kk], na0);
          na1 = MFMA16(*reinterpret_cast<const short8*>(&s_win[((32 + kk) * 64 + lane) * 8]), nf[kk], na1);
        }
      }
    }
  }
}

__global__ void out_head(const unsigned short* __restrict__ h2,
                         const float* __restrict__ W_out,
                         const float* __restrict__ b_out,
                         float* __restrict__ out) {
  int b = blockIdx.x;      // 64
  int lane = threadIdx.x;  // 64 (one wave)
  float s = 0.f;
  for (int k = lane; k < H_; k += 64)
    s += bf2f(h2[(size_t)b * H_ + k]) * W_out[k];
  #pragma unroll
  for (int off = 32; off; off >>= 1) s += __shfl_down(s, off, 64);
  if (lane == 0) out[b] = sigm(s + b_out[0]);
}

} // namespace

extern "C" void kernel_launch(void* const* d_in, const int* in_sizes, int n_in,
                              void* d_out, int out_size, void* d_ws, size_t ws_size,
                              hipStream_t stream) {
  const float* x    = (const float*)d_in[0];
  const float* Wih0 = (const float*)d_in[1];
  const float* Whh0 = (const float*)d_in[2];
  const float* bih0 = (const float*)d_in[3];
  const float* bhh0 = (const float*)d_in[4];
  const float* Wih1 = (const float*)d_in[5];
  const float* Whh1 = (const float*)d_in[6];
  const float* bih1 = (const float*)d_in[7];
  const float* bhh1 = (const float*)d_in[8];
  const float* Wout = (const float*)d_in[9];
  const float* bout = (const float*)d_in[10];
  float* out = (float*)d_out;

  char* ws = (char*)d_ws;
  size_t off = 0;
  auto alloc = [&](size_t bytes) -> char* {
    char* p = ws + off;
    off += (bytes + 4095) & ~(size_t)4095;   // 4KB-align every region
    return p;
  };
  const size_t REC = (size_t)(T_ + 1) * BH * 2;       // 67.2 MB (513 slabs)

  unsigned* bar        = (unsigned*)alloc(8192);      // 2048 u32: arrive+release
  unsigned short* xb   = (unsigned short*)alloc((size_t)B_ * T_ * I_ * 2);
  unsigned short* wih0 = (unsigned short*)alloc((size_t)4 * H_ * I_ * 2);
  unsigned short* whh0 = (unsigned short*)alloc((size_t)4 * H_ * H_ * 2);
  unsigned short* wih1 = (unsigned short*)alloc((size_t)4 * H_ * H_ * 2);
  unsigned short* whh1 = (unsigned short*)alloc((size_t)4 * H_ * H_ * 2);
  unsigned short* h1   = (unsigned short*)alloc(REC);
  unsigned short* h2   = (unsigned short*)alloc(REC);

  auto cvt = [&](const float* s, unsigned short* d, int nelem) {
    int n4 = nelem / 4;
    cvt_bf16_k<<<(n4 + 255) / 256, 256, 0, stream>>>(s, d, n4);
  };
  cvt(x,    xb,   B_ * T_ * I_);
  cvt(Wih0, wih0, 4 * H_ * I_);
  cvt(Whh0, whh0, 4 * H_ * H_);
  cvt(Wih1, wih1, 4 * H_ * H_);
  cvt(Whh1, whh1, 4 * H_ * H_);
  zero_init_k<<<(BH + 255) / 256, 256, 0, stream>>>(h1, h2, bar);

  lstm_fused<<<NWG, NTHR, 0, stream>>>(
      xb, wih0, whh0, bih0, bhh0, wih1, whh1, bih1, bhh1, h1, h2, bar);

  // final h2 = layer1 step 511 output = slab 512 -> reversed offset 0
  out_head<<<B_, 64, 0, stream>>>(h2, Wout, bout, out);
}

// Round 16
// 4358.328 us; speedup vs baseline: 1.3375x; 1.1099x over previous
//
#include <hip/hip_runtime.h>
#include <hip/hip_bf16.h>

// LSTM (B=64,T=512,I=512,H=1024,O=1), 2 layers + sigmoid head.
// R16 = R12 body (fragment-order conflict-free LDS, shadow in-GEMM after the
//       arrive -- R13/R14/R15 all proved that window is the only free slot)
//     + R11 direct barrier poll (ALL waves poll the 32 arrive lines; the
//       leader->release extra MALL hop of R12 is removed).
//  - Layer-pipelined: WGs 0..127 layer0 (step p), 128..255 layer1 (step p-2),
//    514 phases, one coupled 256-WG barrier (decoupling regressed in R14).
//  - Operand swap: A = W rows (unit-major) from LDS fragments, B = h/x.
//    Lane holds all 4 gates (regs) of one unit for one batch: zero-shuffle ew.
//  - Fragment-order LDS: A-fragment (rt,kk) at slot ((rt*NK+kk)*64+lane)*16B
//    -> each wave read is 64 consecutive 16B slots, conflict-free.
//  - h protocol (R8): sc0sc1 u64 write-through stores, plain cached reads of
//    per-step FRESH slabs in REVERSE address order, RELAXED arrive RMW after
//    vmcnt-draining __syncthreads, workgroup-scope acquire fence only.

namespace {

constexpr int B_ = 64, T_ = 512, I_ = 512, H_ = 1024;
constexpr int NWG = 256, NTHR = 256;
constexpr int BH = B_ * H_;

typedef __attribute__((ext_vector_type(8))) short short8;
typedef __attribute__((ext_vector_type(4))) float f32x4;

#define MFMA16(a, b, c) __builtin_amdgcn_mfma_f32_16x16x32_bf16((a), (b), (c), 0, 0, 0)

__device__ __forceinline__ float sigm(float x)  { return 1.f / (1.f + __expf(-x)); }
__device__ __forceinline__ float tanhx(float x) { return 2.f / (1.f + __expf(-2.f * x)) - 1.f; }

__device__ __forceinline__ unsigned f2bf(float f) {
  unsigned u = __float_as_uint(f);
  unsigned rnd = 0x7FFFu + ((u >> 16) & 1u);
  return (u + rnd) >> 16;   // low 16 bits valid
}
__device__ __forceinline__ float bf2f(unsigned short s) {
  return __uint_as_float(((unsigned)s) << 16);
}

__global__ void cvt_bf16_k(const float* __restrict__ src, unsigned short* __restrict__ dst, int n4) {
  int i = blockIdx.x * 256 + threadIdx.x;
  if (i >= n4) return;
  float4 v = reinterpret_cast<const float4*>(src)[i];
  ushort4 o;
  o.x = (unsigned short)f2bf(v.x); o.y = (unsigned short)f2bf(v.y);
  o.z = (unsigned short)f2bf(v.z); o.w = (unsigned short)f2bf(v.w);
  reinterpret_cast<ushort4*>(dst)[i] = o;
}

// zero slab-0 of both records (at REVERSED position T_) and the barrier region
__global__ void zero_init_k(unsigned short* __restrict__ h1, unsigned short* __restrict__ h2,
                            unsigned* __restrict__ bar) {
  int i = blockIdx.x * 256 + threadIdx.x;
  if (i < BH) h1[(size_t)T_ * BH + i] = 0;
  if (i < BH) h2[(size_t)T_ * BH + i] = 0;
  if (i < 1024) bar[i] = 0;   // 32 arrive lines (stride 32)
}

// bars: arrive line g at bars[g*32] (g<32; 8 WGs each). Monotonic: after all
// arrivals of phase p each counter == 8*(p+1); wait(p): all >= 8*p.
// Records: slab s at rec + (T_-s)*BH (reverse order). Step t: read slab t,
// write slab t+1. Layer1's step-t input = h1 slab t+1.
__global__ __launch_bounds__(NTHR, 1) void lstm_fused(
    const unsigned short* __restrict__ xb,
    const unsigned short* __restrict__ wih0, const unsigned short* __restrict__ whh0,
    const float* __restrict__ bih0, const float* __restrict__ bhh0,
    const unsigned short* __restrict__ wih1, const unsigned short* __restrict__ whh1,
    const float* __restrict__ bih1, const float* __restrict__ bhh1,
    unsigned short* __restrict__ h1rec, unsigned short* __restrict__ h2rec,
    unsigned* __restrict__ bars)
{
  // fragment-order W storage: slot ((rt*NK+kk)*64+lane) holds 8 shorts =
  // row (rt*16 + lane&15), k-slice (lane>>4)*8 within k-tile kk.
  __shared__ unsigned short s_win[32768];   // 64 KB (layer0 uses half)
  __shared__ unsigned short s_whh[32768];   // 64 KB

  const int tid   = threadIdx.x;
  const int wg    = blockIdx.x;       // 0..255
  const int layer = wg >> 7;          // 0..1
  const int lwg   = wg & 127;
  const int wave  = tid >> 6;         // 0..3 -> batch tile
  const int lane  = tid & 63;
  const int j0    = lwg * 8;          // first of 8 hidden units owned
  const int u4    = lane >> 4;        // k-group / unit offset in ew
  const int k0    = u4 * 8;
  const int arow  = wave * 16 + (lane & 15);   // batch row for B fragments

  const unsigned short* w_in = layer ? wih1 : wih0;
  const unsigned short* w_hh = layer ? whh1 : whh0;
  const float* b_i = layer ? bih1 : bih0;
  const float* b_h = layer ? bhh1 : bhh0;
  unsigned short* rec = layer ? h2rec : h1rec;
  const int K_IN = layer ? 1024 : 512;
  const int NKI  = K_IN / 32;         // in-GEMM k-tiles (16 or 32)

  unsigned* grp = bars + (wg >> 3) * 32;   // 32 groups of 8 WGs

  // ---- stage W into fragment-order LDS ----
  for (int c = tid; c < 2 * NKI * 64; c += NTHR) {
    int l  = c & 63;
    int kk = (c >> 6) % NKI;
    int rt = c / (NKI * 64);
    int rr = l & 15, q = l >> 4;
    int grow = (rr & 3) * H_ + j0 + rt * 4 + (rr >> 2);
    *reinterpret_cast<short8*>(&s_win[c * 8]) =
        *reinterpret_cast<const short8*>(&w_in[(size_t)grow * K_IN + kk * 32 + q * 8]);
  }
  for (int c = tid; c < 2 * 32 * 64; c += NTHR) {
    int l  = c & 63;
    int kk = (c >> 6) & 31;
    int rt = c >> 11;
    int rr = l & 15, q = l >> 4;
    int grow = (rr & 3) * H_ + j0 + rt * 4 + (rr >> 2);
    *reinterpret_cast<short8*>(&s_whh[c * 8]) =
        *reinterpret_cast<const short8*>(&w_hh[(size_t)grow * H_ + kk * 32 + q * 8]);
  }
  float bias0[4], bias1[4];
  #pragma unroll
  for (int g = 0; g < 4; ++g) {
    bias0[g] = b_i[g * H_ + j0 + u4]     + b_h[g * H_ + j0 + u4];
    bias1[g] = b_i[g * H_ + j0 + 4 + u4] + b_h[g * H_ + j0 + 4 + u4];
  }
  __syncthreads();

  float cst0 = 0.f, cst1 = 0.f;
  f32x4 na0 = {0.f, 0.f, 0.f, 0.f}, na1 = {0.f, 0.f, 0.f, 0.f};

  // prologue: layer0's in-acc for step 0
  if (layer == 0) {
    const unsigned short* a_in = xb + (size_t)arow * (T_ * I_) + k0;
    #pragma unroll
    for (int kk = 0; kk < 16; ++kk) {
      short8 bv = *reinterpret_cast<const short8*>(a_in + kk * 32);
      na0 = MFMA16(*reinterpret_cast<const short8*>(&s_win[(kk * 64 + lane) * 8]),        bv, na0);
      na1 = MFMA16(*reinterpret_cast<const short8*>(&s_win[((16 + kk) * 64 + lane) * 8]), bv, na1);
    }
  }

  for (int p = 0; p <= T_ + 1; ++p) {
    // ---- wait for phase p: ALL waves poll the 32 arrive lines directly ----
    if (p > 0) {
      const unsigned tgt = (unsigned)p * 8u;
      for (;;) {
        unsigned v = 0xFFFFFFFFu;
        if (lane < 32)
          v = __hip_atomic_load(bars + lane * 32, __ATOMIC_RELAXED, __HIP_MEMORY_SCOPE_AGENT);
        if (__all((int)(lane >= 32 || v >= tgt))) break;
        __builtin_amdgcn_s_sleep(1);
      }
      __builtin_amdgcn_fence(__ATOMIC_ACQUIRE, "workgroup");  // ordering only, no cache ops
    }

    f32x4 acc0 = na0, acc1 = na1;
    const int t = layer ? p - 2 : p;

    if (t >= 0 && t < T_) {
      // ---- hh GEMM: B = h[slab t] (cached), A = s_whh fragments ----
      const unsigned short* a_h = rec + (size_t)(T_ - t) * BH + (size_t)arow * H_ + k0;
      short8 hf[32];
      #pragma unroll
      for (int kk = 0; kk < 32; ++kk)
        hf[kk] = *reinterpret_cast<const short8*>(a_h + kk * 32);
      #pragma unroll
      for (int kk = 0; kk < 32; ++kk) {
        acc0 = MFMA16(*reinterpret_cast<const short8*>(&s_whh[(kk * 64 + lane) * 8]),        hf[kk], acc0);
        acc1 = MFMA16(*reinterpret_cast<const short8*>(&s_whh[((32 + kk) * 64 + lane) * 8]), hf[kk], acc1);
      }

      // ---- elementwise (zero-shuffle): regs = gates of (unit, batch arow) ----
      float gi0 = sigm(acc0[0] + bias0[0]);
      float gf0 = sigm(acc0[1] + bias0[1]);
      float gg0 = tanhx(acc0[2] + bias0[2]);
      float go0 = sigm(acc0[3] + bias0[3]);
      cst0 = gf0 * cst0 + gi0 * gg0;
      float hv0 = go0 * tanhx(cst0);

      float gi1 = sigm(acc1[0] + bias1[0]);
      float gf1 = sigm(acc1[1] + bias1[1]);
      float gg1 = tanhx(acc1[2] + bias1[2]);
      float go1 = sigm(acc1[3] + bias1[3]);
      cst1 = gf1 * cst1 + gi1 * gg1;
      float hv1 = go1 * tanhx(cst1);

      unsigned a16 = f2bf(hv0) & 0xFFFFu;
      unsigned b16 = f2bf(hv1) & 0xFFFFu;
      unsigned a1 = __shfl(a16, (lane & 15) | 16, 64);
      unsigned a2 = __shfl(a16, (lane & 15) | 32, 64);
      unsigned a3 = __shfl(a16, (lane & 15) | 48, 64);
      unsigned b1 = __shfl(b16, (lane & 15) | 16, 64);
      unsigned b2 = __shfl(b16, (lane & 15) | 32, 64);
      unsigned b3 = __shfl(b16, (lane & 15) | 48, 64);
      if (lane < 16) {
        unsigned long long qa = (unsigned long long)(a16 | (a1 << 16)) |
                                ((unsigned long long)(a2 | (a3 << 16)) << 32);
        unsigned long long qb = (unsigned long long)(b16 | (b1 << 16)) |
                                ((unsigned long long)(b2 | (b3 << 16)) << 32);
        unsigned long long* dst = (unsigned long long*)
            (rec + (size_t)(T_ - t - 1) * BH + (size_t)(wave * 16 + lane) * H_ + j0);
        __hip_atomic_store(dst,     qa, __ATOMIC_RELAXED, __HIP_MEMORY_SCOPE_AGENT);
        __hip_atomic_store(dst + 1, qb, __ATOMIC_RELAXED, __HIP_MEMORY_SCOPE_AGENT);
      }
    }

    // ---- arrive: __syncthreads drains vmcnt(0) => stores ack'd at MALL ----
    __syncthreads();
    if (tid == 0)
      __hip_atomic_fetch_add(grp, 1u, __ATOMIC_RELAXED, __HIP_MEMORY_SCOPE_AGENT);

    // ---- shadow: in-GEMM for this WG's next step (post-arrive window --
    //      R13/R14/R15 established this is the only free slot) ----
    na0 = (f32x4){0.f, 0.f, 0.f, 0.f};
    na1 = (f32x4){0.f, 0.f, 0.f, 0.f};
    const int tn = layer ? p - 1 : p + 1;
    if (tn >= 0 && tn < T_) {
      if (layer == 0) {
        const unsigned short* a_in = xb + (size_t)arow * (T_ * I_) + (size_t)tn * I_ + k0;
        #pragma unroll
        for (int kk = 0; kk < 16; ++kk) {
          short8 bv = *reinterpret_cast<const short8*>(a_in + kk * 32);
          na0 = MFMA16(*reinterpret_cast<const short8*>(&s_win[(kk * 64 + lane) * 8]),        bv, na0);
          na1 = MFMA16(*reinterpret_cast<const short8*>(&s_win[((16 + kk) * 64 + lane) * 8]), bv, na1);
        }
      } else {
        // input = h1 slab tn+1, written phase tn (= p-1), sealed by wait(p)
        const unsigned short* a_in = h1rec + (size_t)(T_ - 1 - tn) * BH + (size_t)arow * H_ + k0;
        #pragma unroll
        for (int kk = 0; kk < 32; ++kk) {
          short8 bv = *reinterpret_cast<const short8*>(a_in + kk * 32);
          na0 = MFMA16(*reinterpret_cast<const short8*>(&s_win[(kk * 64 + lane) * 8]),        bv, na0);
          na1 = MFMA16(*reinterpret_cast<const short8*>(&s_win[((32 + kk) * 64 + lane) * 8]), bv, na1);
        }
      }
    }
  }
}

__global__ void out_head(const unsigned short* __restrict__ h2,
                         const float* __restrict__ W_out,
                         const float* __restrict__ b_out,
                         float* __restrict__ out) {
  int b = blockIdx.x;      // 64
  int lane = threadIdx.x;  // 64 (one wave)
  float s = 0.f;
  for (int k = lane; k < H_; k += 64)
    s += bf2f(h2[(size_t)b * H_ + k]) * W_out[k];
  #pragma unroll
  for (int off = 32; off; off >>= 1) s += __shfl_down(s, off, 64);
  if (lane == 0) out[b] = sigm(s + b_out[0]);
}

} // namespace

extern "C" void kernel_launch(void* const* d_in, const int* in_sizes, int n_in,
                              void* d_out, int out_size, void* d_ws, size_t ws_size,
                              hipStream_t stream) {
  const float* x    = (const float*)d_in[0];
  const float* Wih0 = (const float*)d_in[1];
  const float* Whh0 = (const float*)d_in[2];
  const float* bih0 = (const float*)d_in[3];
  const float* bhh0 = (const float*)d_in[4];
  const float* Wih1 = (const float*)d_in[5];
  const float* Whh1 = (const float*)d_in[6];
  const float* bih1 = (const float*)d_in[7];
  const float* bhh1 = (const float*)d_in[8];
  const float* Wout = (const float*)d_in[9];
  const float* bout = (const float*)d_in[10];
  float* out = (float*)d_out;

  char* ws = (char*)d_ws;
  size_t off = 0;
  auto alloc = [&](size_t bytes) -> char* {
    char* p = ws + off;
    off += (bytes + 4095) & ~(size_t)4095;   // 4KB-align every region
    return p;
  };
  const size_t REC = (size_t)(T_ + 1) * BH * 2;       // 67.2 MB (513 slabs)

  unsigned* bar        = (unsigned*)alloc(4096);      // 1024 u32 (32 lines)
  unsigned short* xb   = (unsigned short*)alloc((size_t)B_ * T_ * I_ * 2);
  unsigned short* wih0 = (unsigned short*)alloc((size_t)4 * H_ * I_ * 2);
  unsigned short* whh0 = (unsigned short*)alloc((size_t)4 * H_ * H_ * 2);
  unsigned short* wih1 = (unsigned short*)alloc((size_t)4 * H_ * H_ * 2);
  unsigned short* whh1 = (unsigned short*)alloc((size_t)4 * H_ * H_ * 2);
  unsigned short* h1   = (unsigned short*)alloc(REC);
  unsigned short* h2   = (unsigned short*)alloc(REC);

  auto cvt = [&](const float* s, unsigned short* d, int nelem) {
    int n4 = nelem / 4;
    cvt_bf16_k<<<(n4 + 255) / 256, 256, 0, stream>>>(s, d, n4);
  };
  cvt(x,    xb,   B_ * T_ * I_);
  cvt(Wih0, wih0, 4 * H_ * I_);
  cvt(Whh0, whh0, 4 * H_ * H_);
  cvt(Wih1, wih1, 4 * H_ * H_);
  cvt(Whh1, whh1, 4 * H_ * H_);
  zero_init_k<<<(BH + 255) / 256, 256, 0, stream>>>(h1, h2, bar);

  lstm_fused<<<NWG, NTHR, 0, stream>>>(
      xb, wih0, whh0, bih0, bhh0, wih1, whh1, bih1, bhh1, h1, h2, bar);

  // final h2 = layer1 step 511 output = slab 512 -> reversed offset 0
  out_head<<<B_, 64, 0, stream>>>(h2, Wout, bout, out);
}